// Round 1
// baseline (2651.707 us; speedup 1.0000x reference)
//
#include <hip/hip_runtime.h>
#include <math.h>

// Problem constants (B=2, S=1024, H=2048, E=16, K=4, CAP=768)
#define NTOK 2048
#define HDIM 2048
#define HHALF 1024
#define EDIM 16
#define CAPV 768
#define TOPK 4

// ---------------- fp32 SGEMM: C = act(A[M,K] @ W[K,N] + bias[N]) ----------------
// Block 256 threads, tile 128x128, TK=16, 8x8 outputs/thread.
// Requires M%128==0, N%128==0, K%16==0 (true for all launches here).
template <int RELU>
__global__ __launch_bounds__(256) void sgemm_bias(
    const float* __restrict__ A, const float* __restrict__ W,
    const float* __restrict__ bias, float* __restrict__ C,
    int M, int N, int K) {
  __shared__ float As[16][128 + 4];  // [k][m] transposed store
  __shared__ float Ws[16][128 + 4];  // [k][n]
  const int tid = threadIdx.x;
  const int tx = tid & 15;   // 16 col-groups
  const int ty = tid >> 4;   // 16 row-groups
  const int m0 = blockIdx.y * 128;
  const int n0 = blockIdx.x * 128;

  float acc[8][8];
#pragma unroll
  for (int i = 0; i < 8; ++i)
#pragma unroll
    for (int j = 0; j < 8; ++j) acc[i][j] = 0.0f;

  const int a_k = tid & 15;        // staging: A col (k), 8 row passes
  const int a_r = tid >> 4;
  const int w_n = tid & 127;       // staging: W col (n), 8 k passes
  const int w_k = tid >> 7;

  for (int k0 = 0; k0 < K; k0 += 16) {
#pragma unroll
    for (int p = 0; p < 8; ++p) {
      int row = a_r + p * 16;
      As[a_k][row] = A[(size_t)(m0 + row) * K + (k0 + a_k)];
    }
#pragma unroll
    for (int p = 0; p < 8; ++p) {
      int kk = w_k + p * 2;
      Ws[kk][w_n] = W[(size_t)(k0 + kk) * N + (n0 + w_n)];
    }
    __syncthreads();
#pragma unroll
    for (int kk = 0; kk < 16; ++kk) {
      float4 a0 = *(const float4*)&As[kk][ty * 8];
      float4 a1 = *(const float4*)&As[kk][ty * 8 + 4];
      float4 w0 = *(const float4*)&Ws[kk][tx * 4];
      float4 w1 = *(const float4*)&Ws[kk][tx * 4 + 64];
      float a[8] = {a0.x, a0.y, a0.z, a0.w, a1.x, a1.y, a1.z, a1.w};
      float w[8] = {w0.x, w0.y, w0.z, w0.w, w1.x, w1.y, w1.z, w1.w};
#pragma unroll
      for (int i = 0; i < 8; ++i)
#pragma unroll
        for (int j = 0; j < 8; ++j) acc[i][j] = fmaf(a[i], w[j], acc[i][j]);
    }
    __syncthreads();
  }

  // Epilogue: cols are {n0+tx*4 .. +3} and {n0+64+tx*4 .. +3}
  float4 b0 = *(const float4*)&bias[n0 + tx * 4];
  float4 b1 = *(const float4*)&bias[n0 + 64 + tx * 4];
  float bb0[4] = {b0.x, b0.y, b0.z, b0.w};
  float bb1[4] = {b1.x, b1.y, b1.z, b1.w};
#pragma unroll
  for (int i = 0; i < 8; ++i) {
    int row = m0 + ty * 8 + i;
    float4 o0, o1;
    float* p0 = (float*)&o0;
    float* p1 = (float*)&o1;
#pragma unroll
    for (int j = 0; j < 4; ++j) {
      float v0 = acc[i][j] + bb0[j];
      float v1 = acc[i][j + 4] + bb1[j];
      if (RELU) { v0 = fmaxf(v0, 0.0f); v1 = fmaxf(v1, 0.0f); }
      p0[j] = v0; p1[j] = v1;
    }
    *(float4*)&C[(size_t)row * N + n0 + tx * 4] = o0;
    *(float4*)&C[(size_t)row * N + n0 + 64 + tx * 4] = o1;
  }
}

// ---------------- Skinny logits: L[tok,e] = Y[tok,:] @ W2[:,e] + b2[e] ----------------
// grid = NTOK*16/256 blocks; one thread per (token, expert).
__global__ __launch_bounds__(256) void logits_kernel(
    const float* __restrict__ Y, const float* __restrict__ W2,
    const float* __restrict__ b2, float* __restrict__ L, int K) {
  int gid = blockIdx.x * 256 + threadIdx.x;
  int tok = gid >> 4;
  int e = gid & 15;
  const float* y = Y + (size_t)tok * K;
  float acc = 0.0f;
  for (int k = 0; k < K; k += 4) {
    float4 yv = *(const float4*)&y[k];
    acc = fmaf(yv.x, W2[(size_t)(k + 0) * EDIM + e], acc);
    acc = fmaf(yv.y, W2[(size_t)(k + 1) * EDIM + e], acc);
    acc = fmaf(yv.z, W2[(size_t)(k + 2) * EDIM + e], acc);
    acc = fmaf(yv.w, W2[(size_t)(k + 3) * EDIM + e], acc);
  }
  L[gid] = acc + b2[e];
}

// ---------------- Router finalize ----------------
__device__ __forceinline__ void softmax16(const float* __restrict__ L, float* __restrict__ p) {
  float v[16];
  *(float4*)&v[0]  = *(const float4*)&L[0];
  *(float4*)&v[4]  = *(const float4*)&L[4];
  *(float4*)&v[8]  = *(const float4*)&L[8];
  *(float4*)&v[12] = *(const float4*)&L[12];
  float m = v[0];
#pragma unroll
  for (int e = 1; e < 16; ++e) m = fmaxf(m, v[e]);
  float s = 0.0f;
#pragma unroll
  for (int e = 0; e < 16; ++e) { v[e] = expf(v[e] - m); s += v[e]; }
  float inv = 1.0f / s;
#pragma unroll
  for (int e = 0; e < 16; ++e) p[e] = v[e] * inv;
}

__global__ __launch_bounds__(256) void finalize_kernel(
    const float* __restrict__ Lg, const float* __restrict__ Lsi,
    const float* __restrict__ Lsg, const float* __restrict__ Lsc,
    const float* __restrict__ Lsb,
    float* __restrict__ dispatch, float* __restrict__ combine,
    float* __restrict__ router_probs, float* __restrict__ mean_acc) {
  __shared__ float sm[EDIM];
  int tid = threadIdx.x;
  if (tid < EDIM) sm[tid] = 0.0f;
  __syncthreads();

  int tok = blockIdx.x * 256 + tid;
  float pg[16], ps[16], tmp[16], r[16];
  softmax16(Lg + (size_t)tok * EDIM, pg);
  softmax16(Lsi + (size_t)tok * EDIM, ps);
  softmax16(Lsg + (size_t)tok * EDIM, tmp);
#pragma unroll
  for (int e = 0; e < 16; ++e) ps[e] += tmp[e];
  softmax16(Lsc + (size_t)tok * EDIM, tmp);
#pragma unroll
  for (int e = 0; e < 16; ++e) ps[e] += tmp[e];
  softmax16(Lsb + (size_t)tok * EDIM, tmp);
#pragma unroll
  for (int e = 0; e < 16; ++e) ps[e] += tmp[e];

#pragma unroll
  for (int e = 0; e < 16; ++e) {
    float s = ps[e] * 0.5f;                 // / len(available_modalities)
    r[e] = 0.7f * pg[e] + 0.3f * s;         // ALPHA blend
  }

  // router_probs out
#pragma unroll
  for (int e = 0; e < 16; e += 4) {
    float4 o = {r[e], r[e + 1], r[e + 2], r[e + 3]};
    *(float4*)&router_probs[(size_t)tok * EDIM + e] = o;
  }

  // mean probs accumulation (block-local then one atomic per expert per block)
#pragma unroll
  for (int e = 0; e < 16; ++e) atomicAdd(&sm[e], r[e]);

  // top-4 with first-index tie-break (matches lax.top_k set semantics)
  bool used[16];
#pragma unroll
  for (int e = 0; e < 16; ++e) used[e] = false;
  int idx[TOPK];
  float tp[TOPK];
  float tsum = 0.0f;
#pragma unroll
  for (int j = 0; j < TOPK; ++j) {
    float best = -1.0f;
    int bi = 0;
#pragma unroll
    for (int e = 0; e < 16; ++e) {
      bool take = (!used[e]) && (r[e] > best);
      best = take ? r[e] : best;
      bi = take ? e : bi;
    }
    used[bi] = true;
    idx[j] = bi;
    tp[j] = best;
    tsum += best;
  }
  float invt = 1.0f / tsum;
#pragma unroll
  for (int j = 0; j < TOPK; ++j) {
    size_t off = ((size_t)tok * EDIM + idx[j]) * CAPV;  // cap slot 0
    dispatch[off] = 1.0f;
    combine[off] = tp[j] * invt;
  }

  __syncthreads();
  if (tid < EDIM) atomicAdd(&mean_acc[tid], sm[tid]);
}

__global__ void aux_kernel(const float* __restrict__ mean_acc, float* __restrict__ out_aux) {
  if (threadIdx.x == 0 && blockIdx.x == 0) {
    float s = 0.0f;
    for (int e = 0; e < EDIM; ++e) {
      float m = mean_acc[e] * (1.0f / (float)NTOK);
      s += m * logf(m * (float)EDIM + 1e-9f);
    }
    *out_aux = s;
  }
}

// ---------------- launch ----------------
// ws layout (float offsets): bufA[4M] bufB[4M] bufC0[2M] bufC1[2M] L0..L4[5*32768] mean[16]
#define WS_BUFA 0
#define WS_BUFB (4u * 1024u * 1024u)
#define WS_BUFC0 (8u * 1024u * 1024u)
#define WS_BUFC1 (10u * 1024u * 1024u)
#define WS_L (12u * 1024u * 1024u)
#define WS_MEAN (WS_L + 5u * NTOK * EDIM)

extern "C" void kernel_launch(void* const* d_in, const int* in_sizes, int n_in,
                              void* d_out, int out_size, void* d_ws, size_t ws_size,
                              hipStream_t stream) {
  const float* X    = (const float*)d_in[0];
  const float* IMG  = (const float*)d_in[1];
  const float* GEN  = (const float*)d_in[2];
  const float* g_w1 = (const float*)d_in[3];
  const float* g_b1 = (const float*)d_in[4];
  const float* g_w2 = (const float*)d_in[5];
  const float* g_b2 = (const float*)d_in[6];
  const float* m_w1 = (const float*)d_in[7];
  const float* m_b1 = (const float*)d_in[8];
  const float* m_w2 = (const float*)d_in[9];
  const float* m_b2 = (const float*)d_in[10];
  const float* si_w1 = (const float*)d_in[11];
  const float* si_b1 = (const float*)d_in[12];
  const float* si_w2 = (const float*)d_in[13];
  const float* si_b2 = (const float*)d_in[14];
  const float* sg_w1 = (const float*)d_in[15];
  const float* sg_b1 = (const float*)d_in[16];
  const float* sg_w2 = (const float*)d_in[17];
  const float* sg_b2 = (const float*)d_in[18];
  const float* sc_w1 = (const float*)d_in[19];
  const float* sc_b1 = (const float*)d_in[20];
  const float* sc_w2 = (const float*)d_in[21];
  const float* sc_b2 = (const float*)d_in[22];
  const float* sb_w1 = (const float*)d_in[23];
  const float* sb_b1 = (const float*)d_in[24];
  const float* sb_w2 = (const float*)d_in[25];
  const float* sb_b2 = (const float*)d_in[26];

  float* ws = (float*)d_ws;
  float* bufA = ws + WS_BUFA;
  float* bufB = ws + WS_BUFB;
  float* bufC0 = ws + WS_BUFC0;
  float* bufC1 = ws + WS_BUFC1;
  float* L0 = ws + WS_L;                 // g
  float* L1 = L0 + NTOK * EDIM;          // si
  float* L2 = L1 + NTOK * EDIM;          // sg
  float* L3 = L2 + NTOK * EDIM;          // sc
  float* L4 = L3 + NTOK * EDIM;          // sb
  float* meanp = ws + WS_MEAN;

  float* dispatch = (float*)d_out;
  float* combine = dispatch + (size_t)NTOK * EDIM * CAPV;
  float* rp = combine + (size_t)NTOK * EDIM * CAPV;
  float* aux = rp + (size_t)NTOK * EDIM;

  // Zero the (mostly-zero) outputs and the mean accumulator every call.
  hipMemsetAsync(d_out, 0, (size_t)out_size * sizeof(float), stream);
  hipMemsetAsync(meanp, 0, EDIM * sizeof(float), stream);

  dim3 blk(256);
  dim3 gFull(HDIM / 128, NTOK / 128);   // 16x16
  dim3 gHalf(HHALF / 128, NTOK / 128);  // 8x16

  // miss chain first (longest dependency chain)
  sgemm_bias<1><<<gFull, blk, 0, stream>>>(X, m_w1, m_b1, bufA, NTOK, HDIM, HDIM);
  sgemm_bias<0><<<gFull, blk, 0, stream>>>(bufA, m_w2, m_b2, bufB, NTOK, HDIM, HDIM);
  sgemm_bias<1><<<gHalf, blk, 0, stream>>>(bufB, sc_w1, sc_b1, bufC0, NTOK, HHALF, HDIM);
  sgemm_bias<1><<<gHalf, blk, 0, stream>>>(bufB, sb_w1, sb_b1, bufC1, NTOK, HHALF, HDIM);
  logits_kernel<<<NTOK * EDIM / 256, blk, 0, stream>>>(bufC0, sc_w2, sc_b2, L3, HHALF);
  logits_kernel<<<NTOK * EDIM / 256, blk, 0, stream>>>(bufC1, sb_w2, sb_b2, L4, HHALF);
  // generalized router (bufA reusable after miss GEMM consumed it)
  sgemm_bias<1><<<gFull, blk, 0, stream>>>(X, g_w1, g_b1, bufA, NTOK, HDIM, HDIM);
  logits_kernel<<<NTOK * EDIM / 256, blk, 0, stream>>>(bufA, g_w2, g_b2, L0, HDIM);
  // image / genomic specialized routers (bufC reusable after L3/L4)
  sgemm_bias<1><<<gHalf, blk, 0, stream>>>(IMG, si_w1, si_b1, bufC0, NTOK, HHALF, HDIM);
  sgemm_bias<1><<<gHalf, blk, 0, stream>>>(GEN, sg_w1, sg_b1, bufC1, NTOK, HHALF, HDIM);
  logits_kernel<<<NTOK * EDIM / 256, blk, 0, stream>>>(bufC0, si_w2, si_b2, L1, HHALF);
  logits_kernel<<<NTOK * EDIM / 256, blk, 0, stream>>>(bufC1, sg_w2, sg_b2, L2, HHALF);

  finalize_kernel<<<NTOK / 256, blk, 0, stream>>>(L0, L1, L2, L3, L4,
                                                  dispatch, combine, rp, meanp);
  aux_kernel<<<1, 64, 0, stream>>>(meanp, aux);
}

// Round 2
// 1003.344 us; speedup vs baseline: 2.6429x; 2.6429x over previous
//
#include <hip/hip_runtime.h>
#include <math.h>
#include <stdint.h>

// Problem constants (B=2, S=1024, H=2048, E=16, K=4, CAP=768)
#define NTOK 2048
#define HDIM 2048
#define HHALF 1024
#define EDIM 16
#define CAPV 768
#define TOPK 4

typedef __bf16 bf16x8 __attribute__((ext_vector_type(8)));
typedef __bf16 bf16x4 __attribute__((ext_vector_type(4)));
typedef float f32x4 __attribute__((ext_vector_type(4)));

// =====================================================================
// Split-precision bf16 MFMA GEMM.
// C[M,N] = act(A[M,K] @ W[K,N] + bias), with A = Ah+Al, W^T stored as
// WTh/WTl [N][K]. acc += Ah*Wh + Ah*Wl + Al*Wh  (3-term Markidis split,
// ~2^-18 relative error -> top-k safe vs fp32 reference).
// Tile 128x128, BK=64, 4 waves (2x2), 16x16x32 bf16 MFMA.
// LDS tiles are [128 rows][64 k] bf16 = 128B rows, XOR-swizzled:
// 16B chunk c of row r stored at physical chunk c^(r&7)  (G4 recipe).
// Staging uses global_load_lds(16B) with linear LDS dest + inverse-
// swizzled per-lane GLOBAL source (rule #21 both-sides pattern).
// =====================================================================

struct GemmJob {
  const __bf16* Ah; const __bf16* Al;
  const __bf16* Wh; const __bf16* Wl;   // W^T split: [N][K]
  const float* bias;
  float* Cf;                             // fp32 out (or null)
  __bf16* Ch; __bf16* Cl;               // split out (or null)
  int relu;
};
struct GemmBatch { GemmJob j[2]; };

#define GK 2048        // K is 2048 for every GEMM in this problem
#define BKT 64         // K per LDS tile

__device__ __forceinline__ void stage_tile(const __bf16* __restrict__ g,
                                           int grow0, int k0,
                                           __bf16* lbase, int wid, int lane) {
  // Wave `wid` stages rows [wid*32, wid*32+32) of a [128][64]bf16 tile.
  // Each call: 64 lanes x 16B = 8 rows. LDS dest linear; global source
  // chunk is XOR-inverse-swizzled so reads can use the swizzled layout.
  int r_in = lane >> 3;                       // 0..7 row within the 8-row slab
  int swz_elems = ((lane & 7) ^ r_in) << 3;   // (chunk ^ (row&7)) * 8 bf16
#pragma unroll
  for (int i = 0; i < 4; ++i) {
    int row0 = wid * 32 + i * 8;
    const __bf16* src = g + (size_t)(grow0 + row0 + r_in) * GK + k0 + swz_elems;
    __builtin_amdgcn_global_load_lds(
        (const __attribute__((address_space(1))) uint32_t*)src,
        (__attribute__((address_space(3))) uint32_t*)(lbase + row0 * BKT),
        16, 0, 0);
  }
}

__global__ __launch_bounds__(256) void gemm_split(GemmBatch P, int M, int N) {
  __shared__ __align__(16) __bf16 lds[4 * 128 * BKT];  // Ah|Al|Bh|Bl, 64 KB
  __bf16* ldsAh = lds;
  __bf16* ldsAl = lds + 8192;
  __bf16* ldsBh = lds + 16384;
  __bf16* ldsBl = lds + 24576;
  const char* cAh = (const char*)ldsAh;
  const char* cAl = (const char*)ldsAl;
  const char* cBh = (const char*)ldsBh;
  const char* cBl = (const char*)ldsBl;

  const GemmJob J = P.j[blockIdx.z];
  const int m0 = blockIdx.y * 128;
  const int n0 = blockIdx.x * 128;
  const int tid = threadIdx.x;
  const int wid = tid >> 6;
  const int lane = tid & 63;
  const int lane15 = lane & 15;
  const int c0 = lane >> 4;        // 0..3 : k-block-of-8 within MFMA operand
  const int wr = wid >> 1;         // wave row (0..1) -> 64 rows
  const int wc = wid & 1;          // wave col (0..1) -> 64 cols

  // Precomputed swizzled LDS byte offsets for fragment ds_read_b128s.
  int offA[4][2], offB[4][2];
#pragma unroll
  for (int i = 0; i < 4; ++i) {
    int ra = wr * 64 + i * 16 + lane15;
    int rb = wc * 64 + i * 16 + lane15;
#pragma unroll
    for (int ks = 0; ks < 2; ++ks) {
      offA[i][ks] = ra * 128 + (((ks * 4 + c0) ^ (ra & 7)) << 4);
      offB[i][ks] = rb * 128 + (((ks * 4 + c0) ^ (rb & 7)) << 4);
    }
  }

  f32x4 acc[4][4];
#pragma unroll
  for (int i = 0; i < 4; ++i)
#pragma unroll
    for (int j = 0; j < 4; ++j) acc[i][j] = (f32x4){0.f, 0.f, 0.f, 0.f};

  for (int k0 = 0; k0 < GK; k0 += BKT) {
    stage_tile(J.Ah, m0, k0, ldsAh, wid, lane);
    stage_tile(J.Al, m0, k0, ldsAl, wid, lane);
    stage_tile(J.Wh, n0, k0, ldsBh, wid, lane);
    stage_tile(J.Wl, n0, k0, ldsBl, wid, lane);
    __syncthreads();
#pragma unroll
    for (int ks = 0; ks < 2; ++ks) {
      bf16x8 ah[4], al[4], bh[4], bl[4];
#pragma unroll
      for (int i = 0; i < 4; ++i) {
        ah[i] = *(const bf16x8*)(cAh + offA[i][ks]);
        al[i] = *(const bf16x8*)(cAl + offA[i][ks]);
        bh[i] = *(const bf16x8*)(cBh + offB[i][ks]);
        bl[i] = *(const bf16x8*)(cBl + offB[i][ks]);
      }
#pragma unroll
      for (int mi = 0; mi < 4; ++mi)
#pragma unroll
        for (int ni = 0; ni < 4; ++ni) {
          acc[mi][ni] = __builtin_amdgcn_mfma_f32_16x16x32_bf16(
              ah[mi], bh[ni], acc[mi][ni], 0, 0, 0);
          acc[mi][ni] = __builtin_amdgcn_mfma_f32_16x16x32_bf16(
              ah[mi], bl[ni], acc[mi][ni], 0, 0, 0);
          acc[mi][ni] = __builtin_amdgcn_mfma_f32_16x16x32_bf16(
              al[mi], bh[ni], acc[mi][ni], 0, 0, 0);
        }
    }
    __syncthreads();
  }

  // Epilogue: bias + optional ReLU; write fp32 and/or hi/lo split.
  // Verified C/D layout: col = lane&15, row = (lane>>4)*4 + reg  [m89].
#pragma unroll
  for (int mi = 0; mi < 4; ++mi) {
#pragma unroll
    for (int ni = 0; ni < 4; ++ni) {
      int col = n0 + wc * 64 + ni * 16 + lane15;
      float bv = J.bias[col];
      f32x4 v = acc[mi][ni];
#pragma unroll
      for (int j = 0; j < 4; ++j) {
        int row = m0 + wr * 64 + mi * 16 + c0 * 4 + j;
        float x = v[j] + bv;
        if (J.relu) x = fmaxf(x, 0.0f);
        size_t o = (size_t)row * N + col;
        if (J.Cf) J.Cf[o] = x;
        if (J.Ch) {
          __bf16 hh = (__bf16)x;
          J.Ch[o] = hh;
          J.Cl[o] = (__bf16)(x - (float)hh);
        }
      }
    }
  }
}

// ---------------- fp32 -> (hi, lo) bf16 split, elementwise ----------------
__global__ __launch_bounds__(256) void split_f32(const float* __restrict__ in,
                                                 __bf16* __restrict__ h,
                                                 __bf16* __restrict__ l, int n4) {
  int i = blockIdx.x * 256 + threadIdx.x;
  if (i >= n4) return;
  float4 v = ((const float4*)in)[i];
  bf16x4 hv, lv;
  hv.x = (__bf16)v.x; lv.x = (__bf16)(v.x - (float)hv.x);
  hv.y = (__bf16)v.y; lv.y = (__bf16)(v.y - (float)hv.y);
  hv.z = (__bf16)v.z; lv.z = (__bf16)(v.z - (float)hv.z);
  hv.w = (__bf16)v.w; lv.w = (__bf16)(v.w - (float)hv.w);
  ((bf16x4*)h)[i] = hv;
  ((bf16x4*)l)[i] = lv;
}

// ------------- W[K][N] fp32 -> W^T hi/lo bf16 [N][K], LDS transpose -------------
__global__ __launch_bounds__(256) void tsplit(const float* __restrict__ W,
                                              __bf16* __restrict__ Th,
                                              __bf16* __restrict__ Tl,
                                              int Kd, int Nd) {
  __shared__ float t[32][33];
  int tx = threadIdx.x & 31, ty = threadIdx.x >> 5;  // 32 x 8
  int k0 = blockIdx.y * 32, n0 = blockIdx.x * 32;
#pragma unroll
  for (int i = 0; i < 4; ++i) {
    int kk = ty + i * 8;
    t[kk][tx] = W[(size_t)(k0 + kk) * Nd + n0 + tx];
  }
  __syncthreads();
#pragma unroll
  for (int i = 0; i < 4; ++i) {
    int nn = ty + i * 8;
    float v = t[tx][nn];
    __bf16 hh = (__bf16)v;
    size_t o = (size_t)(n0 + nn) * Kd + k0 + tx;
    Th[o] = hh;
    Tl[o] = (__bf16)(v - (float)hh);
  }
}

// ---------------- Skinny logits: L[tok,e] = Y[tok,:] @ W2[:,e] + b2[e] ----------------
__global__ __launch_bounds__(256) void logits_kernel(
    const float* __restrict__ Y, const float* __restrict__ W2,
    const float* __restrict__ b2, float* __restrict__ L, int K) {
  int gid = blockIdx.x * 256 + threadIdx.x;
  int tok = gid >> 4;
  int e = gid & 15;
  const float* y = Y + (size_t)tok * K;
  float acc = 0.0f;
  for (int k = 0; k < K; k += 4) {
    float4 yv = *(const float4*)&y[k];
    acc = fmaf(yv.x, W2[(size_t)(k + 0) * EDIM + e], acc);
    acc = fmaf(yv.y, W2[(size_t)(k + 1) * EDIM + e], acc);
    acc = fmaf(yv.z, W2[(size_t)(k + 2) * EDIM + e], acc);
    acc = fmaf(yv.w, W2[(size_t)(k + 3) * EDIM + e], acc);
  }
  L[gid] = acc + b2[e];
}

// ---------------- Router finalize ----------------
__device__ __forceinline__ void softmax16(const float* __restrict__ L, float* __restrict__ p) {
  float v[16];
  *(float4*)&v[0]  = *(const float4*)&L[0];
  *(float4*)&v[4]  = *(const float4*)&L[4];
  *(float4*)&v[8]  = *(const float4*)&L[8];
  *(float4*)&v[12] = *(const float4*)&L[12];
  float m = v[0];
#pragma unroll
  for (int e = 1; e < 16; ++e) m = fmaxf(m, v[e]);
  float s = 0.0f;
#pragma unroll
  for (int e = 0; e < 16; ++e) { v[e] = expf(v[e] - m); s += v[e]; }
  float inv = 1.0f / s;
#pragma unroll
  for (int e = 0; e < 16; ++e) p[e] = v[e] * inv;
}

__global__ __launch_bounds__(256) void finalize_kernel(
    const float* __restrict__ Lg, const float* __restrict__ Lsi,
    const float* __restrict__ Lsg, const float* __restrict__ Lsc,
    const float* __restrict__ Lsb,
    float* __restrict__ dispatch, float* __restrict__ combine,
    float* __restrict__ router_probs, float* __restrict__ mean_acc) {
  __shared__ float sm[EDIM];
  int tid = threadIdx.x;
  if (tid < EDIM) sm[tid] = 0.0f;
  __syncthreads();

  int tok = blockIdx.x * 256 + tid;
  float pg[16], ps[16], tmp[16], r[16];
  softmax16(Lg + (size_t)tok * EDIM, pg);
  softmax16(Lsi + (size_t)tok * EDIM, ps);
  softmax16(Lsg + (size_t)tok * EDIM, tmp);
#pragma unroll
  for (int e = 0; e < 16; ++e) ps[e] += tmp[e];
  softmax16(Lsc + (size_t)tok * EDIM, tmp);
#pragma unroll
  for (int e = 0; e < 16; ++e) ps[e] += tmp[e];
  softmax16(Lsb + (size_t)tok * EDIM, tmp);
#pragma unroll
  for (int e = 0; e < 16; ++e) ps[e] += tmp[e];

#pragma unroll
  for (int e = 0; e < 16; ++e) {
    float s = ps[e] * 0.5f;                 // / len(available_modalities)
    r[e] = 0.7f * pg[e] + 0.3f * s;         // ALPHA blend
  }

#pragma unroll
  for (int e = 0; e < 16; e += 4) {
    float4 o = {r[e], r[e + 1], r[e + 2], r[e + 3]};
    *(float4*)&router_probs[(size_t)tok * EDIM + e] = o;
  }

#pragma unroll
  for (int e = 0; e < 16; ++e) atomicAdd(&sm[e], r[e]);

  // top-4, first-index tie-break (matches lax.top_k set semantics)
  bool used[16];
#pragma unroll
  for (int e = 0; e < 16; ++e) used[e] = false;
  int idx[TOPK];
  float tp[TOPK];
  float tsum = 0.0f;
#pragma unroll
  for (int j = 0; j < TOPK; ++j) {
    float best = -1.0f;
    int bi = 0;
#pragma unroll
    for (int e = 0; e < 16; ++e) {
      bool take = (!used[e]) && (r[e] > best);
      best = take ? r[e] : best;
      bi = take ? e : bi;
    }
    used[bi] = true;
    idx[j] = bi;
    tp[j] = best;
    tsum += best;
  }
  float invt = 1.0f / tsum;
#pragma unroll
  for (int j = 0; j < TOPK; ++j) {
    size_t off = ((size_t)tok * EDIM + idx[j]) * CAPV;  // cap slot 0
    dispatch[off] = 1.0f;
    combine[off] = tp[j] * invt;
  }

  __syncthreads();
  if (tid < EDIM) atomicAdd(&mean_acc[tid], sm[tid]);
}

__global__ void aux_kernel(const float* __restrict__ mean_acc, float* __restrict__ out_aux) {
  if (threadIdx.x == 0 && blockIdx.x == 0) {
    float s = 0.0f;
    for (int e = 0; e < EDIM; ++e) {
      float m = mean_acc[e] * (1.0f / (float)NTOK);
      s += m * logf(m * (float)EDIM + 1e-9f);
    }
    *out_aux = s;
  }
}

// ---------------- launch ----------------
#define MBYTE (1ull << 20)

extern "C" void kernel_launch(void* const* d_in, const int* in_sizes, int n_in,
                              void* d_out, int out_size, void* d_ws, size_t ws_size,
                              hipStream_t stream) {
  const float* X    = (const float*)d_in[0];
  const float* IMG  = (const float*)d_in[1];
  const float* GEN  = (const float*)d_in[2];
  const float* g_w1 = (const float*)d_in[3];
  const float* g_b1 = (const float*)d_in[4];
  const float* g_w2 = (const float*)d_in[5];
  const float* g_b2 = (const float*)d_in[6];
  const float* m_w1 = (const float*)d_in[7];
  const float* m_b1 = (const float*)d_in[8];
  const float* m_w2 = (const float*)d_in[9];
  const float* m_b2 = (const float*)d_in[10];
  const float* si_w1 = (const float*)d_in[11];
  const float* si_b1 = (const float*)d_in[12];
  const float* si_w2 = (const float*)d_in[13];
  const float* si_b2 = (const float*)d_in[14];
  const float* sg_w1 = (const float*)d_in[15];
  const float* sg_b1 = (const float*)d_in[16];
  const float* sg_w2 = (const float*)d_in[17];
  const float* sg_b2 = (const float*)d_in[18];
  const float* sc_w1 = (const float*)d_in[19];
  const float* sc_b1 = (const float*)d_in[20];
  const float* sc_w2 = (const float*)d_in[21];
  const float* sc_b2 = (const float*)d_in[22];
  const float* sb_w1 = (const float*)d_in[23];
  const float* sb_b1 = (const float*)d_in[24];
  const float* sb_w2 = (const float*)d_in[25];
  const float* sb_b2 = (const float*)d_in[26];

  char* wsb = (char*)d_ws;
  // Region plan (~81 MB peak, lifetimes disjoint by stream order):
  __bf16* AXh = (__bf16*)(wsb + 0 * MBYTE);    // X split -> later MISS -> later GEN
  __bf16* AXl = (__bf16*)(wsb + 8 * MBYTE);
  __bf16* W1h = (__bf16*)(wsb + 16 * MBYTE);
  __bf16* W1l = (__bf16*)(wsb + 24 * MBYTE);
  __bf16* W2h = (__bf16*)(wsb + 32 * MBYTE);
  __bf16* W2l = (__bf16*)(wsb + 40 * MBYTE);
  __bf16* H1h = (__bf16*)(wsb + 48 * MBYTE);   // hidden split -> later YSC/YSB -> IMG split
  __bf16* H1l = (__bf16*)(wsb + 56 * MBYTE);
  float*  YG  = (float*)(wsb + 64 * MBYTE);    // fp32 hidden (g) -> later YSI/YSG
  float*  YSC = (float*)(wsb + 48 * MBYTE);
  float*  YSB = (float*)(wsb + 56 * MBYTE);
  float*  YSI = (float*)(wsb + 64 * MBYTE);
  float*  YSG = (float*)(wsb + 72 * MBYTE);
  __bf16* MISSh = AXh; __bf16* MISSl = AXl;
  __bf16* IMGh = H1h;  __bf16* IMGl = H1l;
  __bf16* GENh = AXh;  __bf16* GENl = AXl;
  float* L0 = (float*)(wsb + 80 * MBYTE);
  float* L1 = L0 + NTOK * EDIM;
  float* L2 = L1 + NTOK * EDIM;
  float* L3 = L2 + NTOK * EDIM;
  float* L4 = L3 + NTOK * EDIM;
  float* meanp = L4 + NTOK * EDIM;

  float* dispatch = (float*)d_out;
  float* combine = dispatch + (size_t)NTOK * EDIM * CAPV;
  float* rp = combine + (size_t)NTOK * EDIM * CAPV;
  float* aux = rp + (size_t)NTOK * EDIM;

  hipMemsetAsync(d_out, 0, (size_t)out_size * sizeof(float), stream);
  hipMemsetAsync(meanp, 0, EDIM * sizeof(float), stream);

  dim3 blk(256);
  const int n4full = NTOK * HDIM / 4;  // float4 count for a 2048x2048 fp32 array
  dim3 gSplit(n4full / 256);
  dim3 gT_full(HDIM / 32, HDIM / 32);
  dim3 gT_half(HHALF / 32, HDIM / 32);
  dim3 gLog(NTOK * EDIM / 256);
  GemmJob nil{};

  // 1) X split, weight transposes for the two X-consuming GEMMs
  split_f32<<<gSplit, blk, 0, stream>>>(X, AXh, AXl, n4full);
  tsplit<<<gT_full, blk, 0, stream>>>(m_w1, W1h, W1l, HDIM, HDIM);
  tsplit<<<gT_full, blk, 0, stream>>>(g_w1, W2h, W2l, HDIM, HDIM);

  // 2) batched: miss hidden (split out) + g hidden (fp32 out)
  {
    GemmBatch b;
    b.j[0] = {AXh, AXl, W1h, W1l, m_b1, nullptr, H1h, H1l, 1};
    b.j[1] = {AXh, AXl, W2h, W2l, g_b1, YG, nullptr, nullptr, 1};
    gemm_split<<<dim3(HDIM / 128, NTOK / 128, 2), blk, 0, stream>>>(b, NTOK, HDIM);
  }

  // 3) miss = H1 @ m_w2 (no relu), split out into AX region (X is dead)
  tsplit<<<gT_full, blk, 0, stream>>>(m_w2, W1h, W1l, HDIM, HDIM);
  {
    GemmBatch b;
    b.j[0] = {H1h, H1l, W1h, W1l, m_b2, nullptr, MISSh, MISSl, 0};
    b.j[1] = nil;
    gemm_split<<<dim3(HDIM / 128, NTOK / 128, 1), blk, 0, stream>>>(b, NTOK, HDIM);
  }

  // 4) batched: sc/sb hidden from miss (fp32 out into H1 region; H1 is dead)
  tsplit<<<gT_half, blk, 0, stream>>>(sc_w1, W2h, W2l, HDIM, HHALF);
  tsplit<<<gT_half, blk, 0, stream>>>(sb_w1, W1h, W1l, HDIM, HHALF);
  {
    GemmBatch b;
    b.j[0] = {MISSh, MISSl, W2h, W2l, sc_b1, YSC, nullptr, nullptr, 1};
    b.j[1] = {MISSh, MISSl, W1h, W1l, sb_b1, YSB, nullptr, nullptr, 1};
    gemm_split<<<dim3(HHALF / 128, NTOK / 128, 2), blk, 0, stream>>>(b, NTOK, HHALF);
  }

  // 5) logits for g / sc / sb
  logits_kernel<<<gLog, blk, 0, stream>>>(YG, g_w2, g_b2, L0, HDIM);
  logits_kernel<<<gLog, blk, 0, stream>>>(YSC, sc_w2, sc_b2, L3, HHALF);
  logits_kernel<<<gLog, blk, 0, stream>>>(YSB, sb_w2, sb_b2, L4, HHALF);

  // 6) image / genomic specialized routers
  split_f32<<<gSplit, blk, 0, stream>>>(IMG, IMGh, IMGl, n4full);   // H1 region
  split_f32<<<gSplit, blk, 0, stream>>>(GEN, GENh, GENl, n4full);   // AX region
  tsplit<<<gT_half, blk, 0, stream>>>(si_w1, W1h, W1l, HDIM, HHALF);
  tsplit<<<gT_half, blk, 0, stream>>>(sg_w1, W2h, W2l, HDIM, HHALF);
  {
    GemmBatch b;
    b.j[0] = {IMGh, IMGl, W1h, W1l, si_b1, YSI, nullptr, nullptr, 1};
    b.j[1] = {GENh, GENl, W2h, W2l, sg_b1, YSG, nullptr, nullptr, 1};
    gemm_split<<<dim3(HHALF / 128, NTOK / 128, 2), blk, 0, stream>>>(b, NTOK, HHALF);
  }
  logits_kernel<<<gLog, blk, 0, stream>>>(YSI, si_w2, si_b2, L1, HHALF);
  logits_kernel<<<gLog, blk, 0, stream>>>(YSG, sg_w2, sg_b2, L2, HHALF);

  // 7) finalize + aux
  finalize_kernel<<<NTOK / 256, blk, 0, stream>>>(L0, L1, L2, L3, L4,
                                                  dispatch, combine, rp, meanp);
  aux_kernel<<<1, 64, 0, stream>>>(meanp, aux);
}

// Round 3
// 575.211 us; speedup vs baseline: 4.6100x; 1.7443x over previous
//
#include <hip/hip_runtime.h>
#include <math.h>
#include <stdint.h>

// Problem constants (B=2, S=1024, H=2048, E=16, K=4, CAP=768)
#define NTOK 2048
#define HDIM 2048
#define HHALF 1024
#define EDIM 16
#define CAPV 768
#define TOPK 4

typedef __bf16 bf16x8 __attribute__((ext_vector_type(8)));
typedef __bf16 bf16x4 __attribute__((ext_vector_type(4)));
typedef float f32x4 __attribute__((ext_vector_type(4)));

// =====================================================================
// Split-precision bf16 MFMA GEMM (3-term Markidis split, top-k safe).
// Tile 128x128, BK=64, 4 waves (2x2), 16x16x32 bf16 MFMA.
// LDS rows XOR-swizzled via pre-swizzled global source (rule #21).
// =====================================================================

struct GemmJob {
  const __bf16* Ah; const __bf16* Al;
  const __bf16* Wh; const __bf16* Wl;   // W^T split: [N][K]
  const float* bias;
  float* Cf;                             // fp32 out (or null)
  __bf16* Ch; __bf16* Cl;               // split out (or null)
  int relu;
};
struct GemmBatch { GemmJob j[2]; };

#define GK 2048        // K is 2048 for every GEMM in this problem
#define BKT 64         // K per LDS tile

__device__ __forceinline__ void stage_tile(const __bf16* __restrict__ g,
                                           int grow0, int k0,
                                           __bf16* lbase, int wid, int lane) {
  // Wave `wid` stages rows [wid*32, wid*32+32) of a [128][64]bf16 tile.
  // LDS dest linear; global source chunk XOR-inverse-swizzled.
  int r_in = lane >> 3;                       // 0..7 row within the 8-row slab
  int swz_elems = ((lane & 7) ^ r_in) << 3;   // (chunk ^ (row&7)) * 8 bf16
#pragma unroll
  for (int i = 0; i < 4; ++i) {
    int row0 = wid * 32 + i * 8;
    const __bf16* src = g + (size_t)(grow0 + row0 + r_in) * GK + k0 + swz_elems;
    __builtin_amdgcn_global_load_lds(
        (const __attribute__((address_space(1))) uint32_t*)src,
        (__attribute__((address_space(3))) uint32_t*)(lbase + row0 * BKT),
        16, 0, 0);
  }
}

__global__ __launch_bounds__(256) void gemm_split(GemmBatch P, int M, int N) {
  __shared__ __align__(16) __bf16 lds[4 * 128 * BKT];  // Ah|Al|Bh|Bl, 64 KB
  __bf16* ldsAh = lds;
  __bf16* ldsAl = lds + 8192;
  __bf16* ldsBh = lds + 16384;
  __bf16* ldsBl = lds + 24576;
  const char* cAh = (const char*)ldsAh;
  const char* cAl = (const char*)ldsAl;
  const char* cBh = (const char*)ldsBh;
  const char* cBl = (const char*)ldsBl;

  const GemmJob J = P.j[blockIdx.z];
  const int m0 = blockIdx.y * 128;
  const int n0 = blockIdx.x * 128;
  const int tid = threadIdx.x;
  const int wid = tid >> 6;
  const int lane = tid & 63;
  const int lane15 = lane & 15;
  const int c0 = lane >> 4;        // 0..3 : k-block-of-8 within MFMA operand
  const int wr = wid >> 1;         // wave row (0..1) -> 64 rows
  const int wc = wid & 1;          // wave col (0..1) -> 64 cols

  // Precomputed swizzled LDS byte offsets for fragment ds_read_b128s.
  int offA[4][2], offB[4][2];
#pragma unroll
  for (int i = 0; i < 4; ++i) {
    int ra = wr * 64 + i * 16 + lane15;
    int rb = wc * 64 + i * 16 + lane15;
#pragma unroll
    for (int ks = 0; ks < 2; ++ks) {
      offA[i][ks] = ra * 128 + (((ks * 4 + c0) ^ (ra & 7)) << 4);
      offB[i][ks] = rb * 128 + (((ks * 4 + c0) ^ (rb & 7)) << 4);
    }
  }

  f32x4 acc[4][4];
#pragma unroll
  for (int i = 0; i < 4; ++i)
#pragma unroll
    for (int j = 0; j < 4; ++j) acc[i][j] = (f32x4){0.f, 0.f, 0.f, 0.f};

  for (int k0 = 0; k0 < GK; k0 += BKT) {
    stage_tile(J.Ah, m0, k0, ldsAh, wid, lane);
    stage_tile(J.Al, m0, k0, ldsAl, wid, lane);
    stage_tile(J.Wh, n0, k0, ldsBh, wid, lane);
    stage_tile(J.Wl, n0, k0, ldsBl, wid, lane);
    __syncthreads();
#pragma unroll
    for (int ks = 0; ks < 2; ++ks) {
      bf16x8 ah[4], al[4], bh[4], bl[4];
#pragma unroll
      for (int i = 0; i < 4; ++i) {
        ah[i] = *(const bf16x8*)(cAh + offA[i][ks]);
        al[i] = *(const bf16x8*)(cAl + offA[i][ks]);
        bh[i] = *(const bf16x8*)(cBh + offB[i][ks]);
        bl[i] = *(const bf16x8*)(cBl + offB[i][ks]);
      }
#pragma unroll
      for (int mi = 0; mi < 4; ++mi)
#pragma unroll
        for (int ni = 0; ni < 4; ++ni) {
          acc[mi][ni] = __builtin_amdgcn_mfma_f32_16x16x32_bf16(
              ah[mi], bh[ni], acc[mi][ni], 0, 0, 0);
          acc[mi][ni] = __builtin_amdgcn_mfma_f32_16x16x32_bf16(
              ah[mi], bl[ni], acc[mi][ni], 0, 0, 0);
          acc[mi][ni] = __builtin_amdgcn_mfma_f32_16x16x32_bf16(
              al[mi], bh[ni], acc[mi][ni], 0, 0, 0);
        }
    }
    __syncthreads();
  }

  // Epilogue: bias + optional ReLU; write fp32 and/or hi/lo split.
  // Verified C/D layout: col = lane&15, row = (lane>>4)*4 + reg  [m89].
#pragma unroll
  for (int mi = 0; mi < 4; ++mi) {
#pragma unroll
    for (int ni = 0; ni < 4; ++ni) {
      int col = n0 + wc * 64 + ni * 16 + lane15;
      float bv = J.bias[col];
      f32x4 v = acc[mi][ni];
#pragma unroll
      for (int j = 0; j < 4; ++j) {
        int row = m0 + wr * 64 + mi * 16 + c0 * 4 + j;
        float x = v[j] + bv;
        if (J.relu) x = fmaxf(x, 0.0f);
        size_t o = (size_t)row * N + col;
        if (J.Cf) J.Cf[o] = x;
        if (J.Ch) {
          __bf16 hh = (__bf16)x;
          J.Ch[o] = hh;
          J.Cl[o] = (__bf16)(x - (float)hh);
        }
      }
    }
  }
}

// ---------------- fp32 -> (hi, lo) bf16 split, elementwise ----------------
__global__ __launch_bounds__(256) void split_f32(const float* __restrict__ in,
                                                 __bf16* __restrict__ h,
                                                 __bf16* __restrict__ l, int n4) {
  int i = blockIdx.x * 256 + threadIdx.x;
  if (i >= n4) return;
  float4 v = ((const float4*)in)[i];
  bf16x4 hv, lv;
  hv.x = (__bf16)v.x; lv.x = (__bf16)(v.x - (float)hv.x);
  hv.y = (__bf16)v.y; lv.y = (__bf16)(v.y - (float)hv.y);
  hv.z = (__bf16)v.z; lv.z = (__bf16)(v.z - (float)hv.z);
  hv.w = (__bf16)v.w; lv.w = (__bf16)(v.w - (float)hv.w);
  ((bf16x4*)h)[i] = hv;
  ((bf16x4*)l)[i] = lv;
}

// ------------- W[K][N] fp32 -> W^T hi/lo bf16 [N][K], LDS transpose -------------
__global__ __launch_bounds__(256) void tsplit(const float* __restrict__ W,
                                              __bf16* __restrict__ Th,
                                              __bf16* __restrict__ Tl,
                                              int Kd, int Nd) {
  __shared__ float t[32][33];
  int tx = threadIdx.x & 31, ty = threadIdx.x >> 5;  // 32 x 8
  int k0 = blockIdx.y * 32, n0 = blockIdx.x * 32;
#pragma unroll
  for (int i = 0; i < 4; ++i) {
    int kk = ty + i * 8;
    t[kk][tx] = W[(size_t)(k0 + kk) * Nd + n0 + tx];
  }
  __syncthreads();
#pragma unroll
  for (int i = 0; i < 4; ++i) {
    int nn = ty + i * 8;
    float v = t[tx][nn];
    __bf16 hh = (__bf16)v;
    size_t o = (size_t)(n0 + nn) * Kd + k0 + tx;
    Th[o] = hh;
    Tl[o] = (__bf16)(v - (float)hh);
  }
}

// ---------------- Skinny logits: L[tok,e] = Y[tok,:] @ W2[:,e] + b2[e] ----------------
// Lane-parallel K-reduction: lane = (expert e, k-quarter kq); each wave owns
// 2 tokens (shared W2 loads, 2 independent FMA chains); 4 waves/block.
// Grid = NTOK/8 blocks. W2 reads coalesced, y reads lane-group broadcast.
template <int KDIM>
__global__ __launch_bounds__(256) void logits_kernel(
    const float* __restrict__ Y, const float* __restrict__ W2,
    const float* __restrict__ b2, float* __restrict__ L) {
  const int tid = threadIdx.x;
  const int wid = tid >> 6, lane = tid & 63;
  const int e = lane & 15;
  const int kq = lane >> 4;
  const int tok0 = blockIdx.x * 8 + wid * 2;
  const float* y0 = Y + (size_t)tok0 * KDIM;
  const float* y1 = y0 + KDIM;
  constexpr int KQ = KDIM / 4;
  const int kbase = kq * KQ;
  float a0 = 0.f, a1 = 0.f;
#pragma unroll 8
  for (int k = 0; k < KQ; ++k) {
    int kk = kbase + k;
    float w = W2[(size_t)kk * EDIM + e];
    a0 = fmaf(y0[kk], w, a0);
    a1 = fmaf(y1[kk], w, a1);
  }
  // fold the 4 k-quarters (lane bits 4..5)
  a0 += __shfl_xor(a0, 16); a0 += __shfl_xor(a0, 32);
  a1 += __shfl_xor(a1, 16); a1 += __shfl_xor(a1, 32);
  if (lane < 16) {
    float b = b2[e];
    L[(size_t)tok0 * EDIM + e] = a0 + b;
    L[(size_t)(tok0 + 1) * EDIM + e] = a1 + b;
  }
}

// ---------------- Router finalize ----------------
__device__ __forceinline__ void softmax16(const float* __restrict__ L, float* __restrict__ p) {
  float v[16];
  *(float4*)&v[0]  = *(const float4*)&L[0];
  *(float4*)&v[4]  = *(const float4*)&L[4];
  *(float4*)&v[8]  = *(const float4*)&L[8];
  *(float4*)&v[12] = *(const float4*)&L[12];
  float m = v[0];
#pragma unroll
  for (int e = 1; e < 16; ++e) m = fmaxf(m, v[e]);
  float s = 0.0f;
#pragma unroll
  for (int e = 0; e < 16; ++e) { v[e] = expf(v[e] - m); s += v[e]; }
  float inv = 1.0f / s;
#pragma unroll
  for (int e = 0; e < 16; ++e) p[e] = v[e] * inv;
}

__global__ __launch_bounds__(256) void finalize_kernel(
    const float* __restrict__ Lg, const float* __restrict__ Lsi,
    const float* __restrict__ Lsg, const float* __restrict__ Lsc,
    const float* __restrict__ Lsb,
    float* __restrict__ dispatch, float* __restrict__ combine,
    float* __restrict__ router_probs, float* __restrict__ mean_acc) {
  __shared__ float sm[EDIM];
  int tid = threadIdx.x;
  if (tid < EDIM) sm[tid] = 0.0f;
  __syncthreads();

  int tok = blockIdx.x * 256 + tid;
  float pg[16], ps[16], tmp[16], r[16];
  softmax16(Lg + (size_t)tok * EDIM, pg);
  softmax16(Lsi + (size_t)tok * EDIM, ps);
  softmax16(Lsg + (size_t)tok * EDIM, tmp);
#pragma unroll
  for (int e = 0; e < 16; ++e) ps[e] += tmp[e];
  softmax16(Lsc + (size_t)tok * EDIM, tmp);
#pragma unroll
  for (int e = 0; e < 16; ++e) ps[e] += tmp[e];
  softmax16(Lsb + (size_t)tok * EDIM, tmp);
#pragma unroll
  for (int e = 0; e < 16; ++e) ps[e] += tmp[e];

#pragma unroll
  for (int e = 0; e < 16; ++e) {
    float s = ps[e] * 0.5f;                 // / len(available_modalities)
    r[e] = 0.7f * pg[e] + 0.3f * s;         // ALPHA blend
  }

#pragma unroll
  for (int e = 0; e < 16; e += 4) {
    float4 o = {r[e], r[e + 1], r[e + 2], r[e + 3]};
    *(float4*)&router_probs[(size_t)tok * EDIM + e] = o;
  }

#pragma unroll
  for (int e = 0; e < 16; ++e) atomicAdd(&sm[e], r[e]);

  // top-4, first-index tie-break (matches lax.top_k set semantics)
  bool used[16];
#pragma unroll
  for (int e = 0; e < 16; ++e) used[e] = false;
  int idx[TOPK];
  float tp[TOPK];
  float tsum = 0.0f;
#pragma unroll
  for (int j = 0; j < TOPK; ++j) {
    float best = -1.0f;
    int bi = 0;
#pragma unroll
    for (int e = 0; e < 16; ++e) {
      bool take = (!used[e]) && (r[e] > best);
      best = take ? r[e] : best;
      bi = take ? e : bi;
    }
    used[bi] = true;
    idx[j] = bi;
    tp[j] = best;
    tsum += best;
  }
  float invt = 1.0f / tsum;
#pragma unroll
  for (int j = 0; j < TOPK; ++j) {
    size_t off = ((size_t)tok * EDIM + idx[j]) * CAPV;  // cap slot 0
    dispatch[off] = 1.0f;
    combine[off] = tp[j] * invt;
  }

  __syncthreads();
  if (tid < EDIM) atomicAdd(&mean_acc[tid], sm[tid]);
}

__global__ void aux_kernel(const float* __restrict__ mean_acc, float* __restrict__ out_aux) {
  if (threadIdx.x == 0 && blockIdx.x == 0) {
    float s = 0.0f;
    for (int e = 0; e < EDIM; ++e) {
      float m = mean_acc[e] * (1.0f / (float)NTOK);
      s += m * logf(m * (float)EDIM + 1e-9f);
    }
    *out_aux = s;
  }
}

// ---------------- launch ----------------
#define MBYTE (1ull << 20)

extern "C" void kernel_launch(void* const* d_in, const int* in_sizes, int n_in,
                              void* d_out, int out_size, void* d_ws, size_t ws_size,
                              hipStream_t stream) {
  const float* X    = (const float*)d_in[0];
  const float* IMG  = (const float*)d_in[1];
  const float* GEN  = (const float*)d_in[2];
  const float* g_w1 = (const float*)d_in[3];
  const float* g_b1 = (const float*)d_in[4];
  const float* g_w2 = (const float*)d_in[5];
  const float* g_b2 = (const float*)d_in[6];
  const float* m_w1 = (const float*)d_in[7];
  const float* m_b1 = (const float*)d_in[8];
  const float* m_w2 = (const float*)d_in[9];
  const float* m_b2 = (const float*)d_in[10];
  const float* si_w1 = (const float*)d_in[11];
  const float* si_b1 = (const float*)d_in[12];
  const float* si_w2 = (const float*)d_in[13];
  const float* si_b2 = (const float*)d_in[14];
  const float* sg_w1 = (const float*)d_in[15];
  const float* sg_b1 = (const float*)d_in[16];
  const float* sg_w2 = (const float*)d_in[17];
  const float* sg_b2 = (const float*)d_in[18];
  const float* sc_w1 = (const float*)d_in[19];
  const float* sc_b1 = (const float*)d_in[20];
  const float* sc_w2 = (const float*)d_in[21];
  const float* sc_b2 = (const float*)d_in[22];
  const float* sb_w1 = (const float*)d_in[23];
  const float* sb_b1 = (const float*)d_in[24];
  const float* sb_w2 = (const float*)d_in[25];
  const float* sb_b2 = (const float*)d_in[26];

  char* wsb = (char*)d_ws;
  // Region plan (~81 MB peak, lifetimes disjoint by stream order):
  __bf16* AXh = (__bf16*)(wsb + 0 * MBYTE);    // X split -> later MISS -> later GEN
  __bf16* AXl = (__bf16*)(wsb + 8 * MBYTE);
  __bf16* W1h = (__bf16*)(wsb + 16 * MBYTE);
  __bf16* W1l = (__bf16*)(wsb + 24 * MBYTE);
  __bf16* W2h = (__bf16*)(wsb + 32 * MBYTE);
  __bf16* W2l = (__bf16*)(wsb + 40 * MBYTE);
  __bf16* H1h = (__bf16*)(wsb + 48 * MBYTE);   // hidden split -> later YSC/YSB -> IMG split
  __bf16* H1l = (__bf16*)(wsb + 56 * MBYTE);
  float*  YG  = (float*)(wsb + 64 * MBYTE);    // fp32 hidden (g) -> later YSI/YSG
  float*  YSC = (float*)(wsb + 48 * MBYTE);
  float*  YSB = (float*)(wsb + 56 * MBYTE);
  float*  YSI = (float*)(wsb + 64 * MBYTE);
  float*  YSG = (float*)(wsb + 72 * MBYTE);
  __bf16* MISSh = AXh; __bf16* MISSl = AXl;
  __bf16* IMGh = H1h;  __bf16* IMGl = H1l;
  __bf16* GENh = AXh;  __bf16* GENl = AXl;
  float* L0 = (float*)(wsb + 80 * MBYTE);
  float* L1 = L0 + NTOK * EDIM;
  float* L2 = L1 + NTOK * EDIM;
  float* L3 = L2 + NTOK * EDIM;
  float* L4 = L3 + NTOK * EDIM;
  float* meanp = L4 + NTOK * EDIM;

  float* dispatch = (float*)d_out;
  float* combine = dispatch + (size_t)NTOK * EDIM * CAPV;
  float* rp = combine + (size_t)NTOK * EDIM * CAPV;
  float* aux = rp + (size_t)NTOK * EDIM;

  hipMemsetAsync(d_out, 0, (size_t)out_size * sizeof(float), stream);
  hipMemsetAsync(meanp, 0, EDIM * sizeof(float), stream);

  dim3 blk(256);
  const int n4full = NTOK * HDIM / 4;  // float4 count for a 2048x2048 fp32 array
  dim3 gSplit(n4full / 256);
  dim3 gT_full(HDIM / 32, HDIM / 32);
  dim3 gT_half(HHALF / 32, HDIM / 32);
  dim3 gLog(NTOK / 8);
  GemmJob nil{};

  // 1) X split, weight transposes for the two X-consuming GEMMs
  split_f32<<<gSplit, blk, 0, stream>>>(X, AXh, AXl, n4full);
  tsplit<<<gT_full, blk, 0, stream>>>(m_w1, W1h, W1l, HDIM, HDIM);
  tsplit<<<gT_full, blk, 0, stream>>>(g_w1, W2h, W2l, HDIM, HDIM);

  // 2) batched: miss hidden (split out) + g hidden (fp32 out)
  {
    GemmBatch b;
    b.j[0] = {AXh, AXl, W1h, W1l, m_b1, nullptr, H1h, H1l, 1};
    b.j[1] = {AXh, AXl, W2h, W2l, g_b1, YG, nullptr, nullptr, 1};
    gemm_split<<<dim3(HDIM / 128, NTOK / 128, 2), blk, 0, stream>>>(b, NTOK, HDIM);
  }

  // 3) miss = H1 @ m_w2 (no relu), split out into AX region (X is dead)
  tsplit<<<gT_full, blk, 0, stream>>>(m_w2, W1h, W1l, HDIM, HDIM);
  {
    GemmBatch b;
    b.j[0] = {H1h, H1l, W1h, W1l, m_b2, nullptr, MISSh, MISSl, 0};
    b.j[1] = nil;
    gemm_split<<<dim3(HDIM / 128, NTOK / 128, 1), blk, 0, stream>>>(b, NTOK, HDIM);
  }

  // 4) batched: sc/sb hidden from miss (fp32 out into H1 region; H1 is dead)
  tsplit<<<gT_half, blk, 0, stream>>>(sc_w1, W2h, W2l, HDIM, HHALF);
  tsplit<<<gT_half, blk, 0, stream>>>(sb_w1, W1h, W1l, HDIM, HHALF);
  {
    GemmBatch b;
    b.j[0] = {MISSh, MISSl, W2h, W2l, sc_b1, YSC, nullptr, nullptr, 1};
    b.j[1] = {MISSh, MISSl, W1h, W1l, sb_b1, YSB, nullptr, nullptr, 1};
    gemm_split<<<dim3(HHALF / 128, NTOK / 128, 2), blk, 0, stream>>>(b, NTOK, HHALF);
  }

  // 5) logits for g / sc / sb
  logits_kernel<HDIM><<<gLog, blk, 0, stream>>>(YG, g_w2, g_b2, L0);
  logits_kernel<HHALF><<<gLog, blk, 0, stream>>>(YSC, sc_w2, sc_b2, L3);
  logits_kernel<HHALF><<<gLog, blk, 0, stream>>>(YSB, sb_w2, sb_b2, L4);

  // 6) image / genomic specialized routers
  split_f32<<<gSplit, blk, 0, stream>>>(IMG, IMGh, IMGl, n4full);   // H1 region
  split_f32<<<gSplit, blk, 0, stream>>>(GEN, GENh, GENl, n4full);   // AX region
  tsplit<<<gT_half, blk, 0, stream>>>(si_w1, W1h, W1l, HDIM, HHALF);
  tsplit<<<gT_half, blk, 0, stream>>>(sg_w1, W2h, W2l, HDIM, HHALF);
  {
    GemmBatch b;
    b.j[0] = {IMGh, IMGl, W1h, W1l, si_b1, YSI, nullptr, nullptr, 1};
    b.j[1] = {GENh, GENl, W2h, W2l, sg_b1, YSG, nullptr, nullptr, 1};
    gemm_split<<<dim3(HHALF / 128, NTOK / 128, 2), blk, 0, stream>>>(b, NTOK, HHALF);
  }
  logits_kernel<HHALF><<<gLog, blk, 0, stream>>>(YSI, si_w2, si_b2, L1);
  logits_kernel<HHALF><<<gLog, blk, 0, stream>>>(YSG, sg_w2, sg_b2, L2);

  // 7) finalize + aux
  finalize_kernel<<<NTOK / 256, blk, 0, stream>>>(L0, L1, L2, L3, L4,
                                                  dispatch, combine, rp, meanp);
  aux_kernel<<<1, 64, 0, stream>>>(meanp, aux);
}

// Round 4
// 487.307 us; speedup vs baseline: 5.4416x; 1.1804x over previous
//
#include <hip/hip_runtime.h>
#include <math.h>
#include <stdint.h>

// Problem constants (B=2, S=1024, H=2048, E=16, K=4, CAP=768)
#define NTOK 2048
#define HDIM 2048
#define HHALF 1024
#define EDIM 16
#define CAPV 768
#define TOPK 4

typedef __bf16 bf16x8 __attribute__((ext_vector_type(8)));
typedef __bf16 bf16x4 __attribute__((ext_vector_type(4)));
typedef float f32x4 __attribute__((ext_vector_type(4)));

// =====================================================================
// Split-precision bf16 MFMA GEMM (3-term Markidis split, top-k safe).
// Tile 128x128, BK=64, 4 waves (2x2), 16x16x32 bf16 MFMA.
// LDS rows XOR-swizzled via pre-swizzled global source (rule #21).
// Multi-job launches via flat block-id job table.
// =====================================================================

#define GK 2048        // K is 2048 for every GEMM in this problem
#define BKT 64         // K per LDS tile

struct GJob {
  const __bf16* Ah; const __bf16* Al;
  const __bf16* Wh; const __bf16* Wl;   // W^T split: [N][K]
  const float* bias;
  float* Cf;                             // fp32 out (or null)
  __bf16* Ch; __bf16* Cl;               // split out (or null)
  int relu; int N; int blk0;            // N of this job; first flat block id
};
struct GJobs { GJob j[4]; int njobs; };

__device__ __forceinline__ void stage_tile(const __bf16* __restrict__ g,
                                           int grow0, int k0,
                                           __bf16* lbase, int wid, int lane) {
  // Wave `wid` stages rows [wid*32, wid*32+32) of a [128][64]bf16 tile.
  // LDS dest linear; global source chunk XOR-inverse-swizzled.
  int r_in = lane >> 3;                       // 0..7 row within the 8-row slab
  int swz_elems = ((lane & 7) ^ r_in) << 3;   // (chunk ^ (row&7)) * 8 bf16
#pragma unroll
  for (int i = 0; i < 4; ++i) {
    int row0 = wid * 32 + i * 8;
    const __bf16* src = g + (size_t)(grow0 + row0 + r_in) * GK + k0 + swz_elems;
    __builtin_amdgcn_global_load_lds(
        (const __attribute__((address_space(1))) uint32_t*)src,
        (__attribute__((address_space(3))) uint32_t*)(lbase + row0 * BKT),
        16, 0, 0);
  }
}

__global__ __launch_bounds__(256) void gemm_split(GJobs P) {
  __shared__ __align__(16) __bf16 lds[4 * 128 * BKT];  // Ah|Al|Bh|Bl, 64 KB
  __bf16* ldsAh = lds;
  __bf16* ldsAl = lds + 8192;
  __bf16* ldsBh = lds + 16384;
  __bf16* ldsBl = lds + 24576;
  const char* cAh = (const char*)ldsAh;
  const char* cAl = (const char*)ldsAl;
  const char* cBh = (const char*)ldsBh;
  const char* cBl = (const char*)ldsBl;

  // Job lookup from flat block id (scalar, once).
  const int bid = blockIdx.x;
  int ji = 0;
#pragma unroll
  for (int k = 1; k < 4; ++k)
    if (k < P.njobs && bid >= P.j[k].blk0) ji = k;
  const GJob J = P.j[ji];
  const int local = bid - J.blk0;
  const int nbx = J.N >> 7;              // 8 or 16 (power of two)
  const int bx = local & (nbx - 1);
  const int by = local / nbx;
  const int m0 = by * 128;
  const int n0 = bx * 128;

  const int tid = threadIdx.x;
  const int wid = tid >> 6;
  const int lane = tid & 63;
  const int lane15 = lane & 15;
  const int c0 = lane >> 4;        // 0..3 : k-block-of-8 within MFMA operand
  const int wr = wid >> 1;         // wave row (0..1) -> 64 rows
  const int wc = wid & 1;          // wave col (0..1) -> 64 cols

  // Precomputed swizzled LDS byte offsets for fragment ds_read_b128s.
  int offA[4][2], offB[4][2];
#pragma unroll
  for (int i = 0; i < 4; ++i) {
    int ra = wr * 64 + i * 16 + lane15;
    int rb = wc * 64 + i * 16 + lane15;
#pragma unroll
    for (int ks = 0; ks < 2; ++ks) {
      offA[i][ks] = ra * 128 + (((ks * 4 + c0) ^ (ra & 7)) << 4);
      offB[i][ks] = rb * 128 + (((ks * 4 + c0) ^ (rb & 7)) << 4);
    }
  }

  f32x4 acc[4][4];
#pragma unroll
  for (int i = 0; i < 4; ++i)
#pragma unroll
    for (int j = 0; j < 4; ++j) acc[i][j] = (f32x4){0.f, 0.f, 0.f, 0.f};

  for (int k0 = 0; k0 < GK; k0 += BKT) {
    stage_tile(J.Ah, m0, k0, ldsAh, wid, lane);
    stage_tile(J.Al, m0, k0, ldsAl, wid, lane);
    stage_tile(J.Wh, n0, k0, ldsBh, wid, lane);
    stage_tile(J.Wl, n0, k0, ldsBl, wid, lane);
    __syncthreads();
#pragma unroll
    for (int ks = 0; ks < 2; ++ks) {
      bf16x8 ah[4], al[4], bh[4], bl[4];
#pragma unroll
      for (int i = 0; i < 4; ++i) {
        ah[i] = *(const bf16x8*)(cAh + offA[i][ks]);
        al[i] = *(const bf16x8*)(cAl + offA[i][ks]);
        bh[i] = *(const bf16x8*)(cBh + offB[i][ks]);
        bl[i] = *(const bf16x8*)(cBl + offB[i][ks]);
      }
#pragma unroll
      for (int mi = 0; mi < 4; ++mi)
#pragma unroll
        for (int ni = 0; ni < 4; ++ni) {
          acc[mi][ni] = __builtin_amdgcn_mfma_f32_16x16x32_bf16(
              ah[mi], bh[ni], acc[mi][ni], 0, 0, 0);
          acc[mi][ni] = __builtin_amdgcn_mfma_f32_16x16x32_bf16(
              ah[mi], bl[ni], acc[mi][ni], 0, 0, 0);
          acc[mi][ni] = __builtin_amdgcn_mfma_f32_16x16x32_bf16(
              al[mi], bh[ni], acc[mi][ni], 0, 0, 0);
        }
    }
    __syncthreads();
  }

  // Epilogue: bias + optional ReLU; write fp32 and/or hi/lo split.
  // Verified C/D layout: col = lane&15, row = (lane>>4)*4 + reg  [m89].
#pragma unroll
  for (int mi = 0; mi < 4; ++mi) {
#pragma unroll
    for (int ni = 0; ni < 4; ++ni) {
      int col = n0 + wc * 64 + ni * 16 + lane15;
      float bv = J.bias[col];
      f32x4 v = acc[mi][ni];
#pragma unroll
      for (int j = 0; j < 4; ++j) {
        int row = m0 + wr * 64 + mi * 16 + c0 * 4 + j;
        float x = v[j] + bv;
        if (J.relu) x = fmaxf(x, 0.0f);
        size_t o = (size_t)row * J.N + col;
        if (J.Cf) J.Cf[o] = x;
        if (J.Ch) {
          __bf16 hh = (__bf16)x;
          J.Ch[o] = hh;
          J.Cl[o] = (__bf16)(x - (float)hh);
        }
      }
    }
  }
}

// ---------------- fp32 -> (hi, lo) bf16 split, 3 inputs batched ----------------
struct SJob { const float* in; __bf16* h; __bf16* l; };
#define SPLIT_BLKS 4096   // (2048*2048/4) / 256
__global__ __launch_bounds__(256) void split3(SJob a, SJob b, SJob c) {
  int job = blockIdx.x >> 12;
  SJob J = (job == 0) ? a : (job == 1) ? b : c;
  int i = (blockIdx.x & 4095) * 256 + threadIdx.x;
  float4 v = ((const float4*)J.in)[i];
  bf16x4 hv, lv;
  hv.x = (__bf16)v.x; lv.x = (__bf16)(v.x - (float)hv.x);
  hv.y = (__bf16)v.y; lv.y = (__bf16)(v.y - (float)hv.y);
  hv.z = (__bf16)v.z; lv.z = (__bf16)(v.z - (float)hv.z);
  hv.w = (__bf16)v.w; lv.w = (__bf16)(v.w - (float)hv.w);
  ((bf16x4*)J.h)[i] = hv;
  ((bf16x4*)J.l)[i] = lv;
}

// ------- W[2048][Nd] fp32 -> W^T hi/lo bf16 [Nd][2048], 7 weights batched -------
struct TJob { const float* W; __bf16* Th; __bf16* Tl; int Nd; };
struct TJobs { TJob j[7]; };
__global__ __launch_bounds__(256) void tsplit(TJobs P) {
  const TJob J = P.j[blockIdx.z];
  int n0 = blockIdx.x * 32;
  if (n0 >= J.Nd) return;                 // half-width jobs use x < 32
  int k0 = blockIdx.y * 32;
  __shared__ float t[32][33];
  int tx = threadIdx.x & 31, ty = threadIdx.x >> 5;  // 32 x 8
#pragma unroll
  for (int i = 0; i < 4; ++i) {
    int kk = ty + i * 8;
    t[kk][tx] = J.W[(size_t)(k0 + kk) * J.Nd + n0 + tx];
  }
  __syncthreads();
#pragma unroll
  for (int i = 0; i < 4; ++i) {
    int nn = ty + i * 8;
    float v = t[tx][nn];
    __bf16 hh = (__bf16)v;
    size_t o = (size_t)(n0 + nn) * GK + k0 + tx;
    J.Th[o] = hh;
    J.Tl[o] = (__bf16)(v - (float)hh);
  }
}

// ---------------- Skinny logits, 5 routers batched ----------------
// Lane = (expert e, k-quarter kq); each wave owns 2 tokens; 4 waves/block;
// 256 blocks per job.
struct LJob { const float* Y; const float* W2; const float* b2; float* L; int K; };
struct LJobs { LJob j[5]; };
__global__ __launch_bounds__(256) void logits_kernel(LJobs P) {
  const LJob J = P.j[blockIdx.x >> 8];
  const int blk = blockIdx.x & 255;
  const int tid = threadIdx.x;
  const int wid = tid >> 6, lane = tid & 63;
  const int e = lane & 15;
  const int kq = lane >> 4;
  const int tok0 = blk * 8 + wid * 2;
  const float* y0 = J.Y + (size_t)tok0 * J.K;
  const float* y1 = y0 + J.K;
  const int KQ = J.K >> 2;
  const int kbase = kq * KQ;
  float a0 = 0.f, a1 = 0.f;
#pragma unroll 8
  for (int k = 0; k < KQ; ++k) {
    int kk = kbase + k;
    float w = J.W2[(size_t)kk * EDIM + e];
    a0 = fmaf(y0[kk], w, a0);
    a1 = fmaf(y1[kk], w, a1);
  }
  a0 += __shfl_xor(a0, 16); a0 += __shfl_xor(a0, 32);
  a1 += __shfl_xor(a1, 16); a1 += __shfl_xor(a1, 32);
  if (lane < 16) {
    float b = J.b2[e];
    J.L[(size_t)tok0 * EDIM + e] = a0 + b;
    J.L[(size_t)(tok0 + 1) * EDIM + e] = a1 + b;
  }
}

// ---------------- Router finalize ----------------
__device__ __forceinline__ void softmax16(const float* __restrict__ L, float* __restrict__ p) {
  float v[16];
  *(float4*)&v[0]  = *(const float4*)&L[0];
  *(float4*)&v[4]  = *(const float4*)&L[4];
  *(float4*)&v[8]  = *(const float4*)&L[8];
  *(float4*)&v[12] = *(const float4*)&L[12];
  float m = v[0];
#pragma unroll
  for (int e = 1; e < 16; ++e) m = fmaxf(m, v[e]);
  float s = 0.0f;
#pragma unroll
  for (int e = 0; e < 16; ++e) { v[e] = expf(v[e] - m); s += v[e]; }
  float inv = 1.0f / s;
#pragma unroll
  for (int e = 0; e < 16; ++e) p[e] = v[e] * inv;
}

__global__ __launch_bounds__(256) void finalize_kernel(
    const float* __restrict__ Lg, const float* __restrict__ Lsi,
    const float* __restrict__ Lsg, const float* __restrict__ Lsc,
    const float* __restrict__ Lsb,
    float* __restrict__ dispatch, float* __restrict__ combine,
    float* __restrict__ router_probs, float* __restrict__ mean_acc) {
  __shared__ float sm[EDIM];
  int tid = threadIdx.x;
  if (tid < EDIM) sm[tid] = 0.0f;
  __syncthreads();

  int tok = blockIdx.x * 256 + tid;
  float pg[16], ps[16], tmp[16], r[16];
  softmax16(Lg + (size_t)tok * EDIM, pg);
  softmax16(Lsi + (size_t)tok * EDIM, ps);
  softmax16(Lsg + (size_t)tok * EDIM, tmp);
#pragma unroll
  for (int e = 0; e < 16; ++e) ps[e] += tmp[e];
  softmax16(Lsc + (size_t)tok * EDIM, tmp);
#pragma unroll
  for (int e = 0; e < 16; ++e) ps[e] += tmp[e];
  softmax16(Lsb + (size_t)tok * EDIM, tmp);
#pragma unroll
  for (int e = 0; e < 16; ++e) ps[e] += tmp[e];

#pragma unroll
  for (int e = 0; e < 16; ++e) {
    float s = ps[e] * 0.5f;                 // / len(available_modalities)
    r[e] = 0.7f * pg[e] + 0.3f * s;         // ALPHA blend
  }

#pragma unroll
  for (int e = 0; e < 16; e += 4) {
    float4 o = {r[e], r[e + 1], r[e + 2], r[e + 3]};
    *(float4*)&router_probs[(size_t)tok * EDIM + e] = o;
  }

#pragma unroll
  for (int e = 0; e < 16; ++e) atomicAdd(&sm[e], r[e]);

  // top-4, first-index tie-break (matches lax.top_k set semantics)
  bool used[16];
#pragma unroll
  for (int e = 0; e < 16; ++e) used[e] = false;
  int idx[TOPK];
  float tp[TOPK];
  float tsum = 0.0f;
#pragma unroll
  for (int j = 0; j < TOPK; ++j) {
    float best = -1.0f;
    int bi = 0;
#pragma unroll
    for (int e = 0; e < 16; ++e) {
      bool take = (!used[e]) && (r[e] > best);
      best = take ? r[e] : best;
      bi = take ? e : bi;
    }
    used[bi] = true;
    idx[j] = bi;
    tp[j] = best;
    tsum += best;
  }
  float invt = 1.0f / tsum;
#pragma unroll
  for (int j = 0; j < TOPK; ++j) {
    size_t off = ((size_t)tok * EDIM + idx[j]) * CAPV;  // cap slot 0
    dispatch[off] = 1.0f;
    combine[off] = tp[j] * invt;
  }

  __syncthreads();
  if (tid < EDIM) atomicAdd(&mean_acc[tid], sm[tid]);
}

__global__ void aux_kernel(const float* __restrict__ mean_acc, float* __restrict__ out_aux) {
  if (threadIdx.x == 0 && blockIdx.x == 0) {
    float s = 0.0f;
    for (int e = 0; e < EDIM; ++e) {
      float m = mean_acc[e] * (1.0f / (float)NTOK);
      s += m * logf(m * (float)EDIM + 1e-9f);
    }
    *out_aux = s;
  }
}

// ---------------- launch ----------------
#define MBYTE (1ull << 20)

extern "C" void kernel_launch(void* const* d_in, const int* in_sizes, int n_in,
                              void* d_out, int out_size, void* d_ws, size_t ws_size,
                              hipStream_t stream) {
  const float* X    = (const float*)d_in[0];
  const float* IMG  = (const float*)d_in[1];
  const float* GEN  = (const float*)d_in[2];
  const float* g_w1 = (const float*)d_in[3];
  const float* g_b1 = (const float*)d_in[4];
  const float* g_w2 = (const float*)d_in[5];
  const float* g_b2 = (const float*)d_in[6];
  const float* m_w1 = (const float*)d_in[7];
  const float* m_b1 = (const float*)d_in[8];
  const float* m_w2 = (const float*)d_in[9];
  const float* m_b2 = (const float*)d_in[10];
  const float* si_w1 = (const float*)d_in[11];
  const float* si_b1 = (const float*)d_in[12];
  const float* si_w2 = (const float*)d_in[13];
  const float* si_b2 = (const float*)d_in[14];
  const float* sg_w1 = (const float*)d_in[15];
  const float* sg_b1 = (const float*)d_in[16];
  const float* sg_w2 = (const float*)d_in[17];
  const float* sg_b2 = (const float*)d_in[18];
  const float* sc_w1 = (const float*)d_in[19];
  const float* sc_b1 = (const float*)d_in[20];
  const float* sc_w2 = (const float*)d_in[21];
  const float* sc_b2 = (const float*)d_in[22];
  const float* sb_w1 = (const float*)d_in[23];
  const float* sb_b1 = (const float*)d_in[24];
  const float* sb_w2 = (const float*)d_in[25];
  const float* sb_b2 = (const float*)d_in[26];

  char* wsb = (char*)d_ws;
  // Flat region plan (~242 MB, all disjoint — no lifetime aliasing).
  __bf16* Xh   = (__bf16*)(wsb + 0 * MBYTE);
  __bf16* Xl   = (__bf16*)(wsb + 8 * MBYTE);
  __bf16* IMGh = (__bf16*)(wsb + 16 * MBYTE);
  __bf16* IMGl = (__bf16*)(wsb + 24 * MBYTE);
  __bf16* GENh = (__bf16*)(wsb + 32 * MBYTE);
  __bf16* GENl = (__bf16*)(wsb + 40 * MBYTE);
  __bf16* Wmw1h = (__bf16*)(wsb + 48 * MBYTE);
  __bf16* Wmw1l = (__bf16*)(wsb + 56 * MBYTE);
  __bf16* Wgw1h = (__bf16*)(wsb + 64 * MBYTE);
  __bf16* Wgw1l = (__bf16*)(wsb + 72 * MBYTE);
  __bf16* Wmw2h = (__bf16*)(wsb + 80 * MBYTE);
  __bf16* Wmw2l = (__bf16*)(wsb + 88 * MBYTE);
  __bf16* Wsch = (__bf16*)(wsb + 96 * MBYTE);
  __bf16* Wscl = (__bf16*)(wsb + 104 * MBYTE);
  __bf16* Wsbh = (__bf16*)(wsb + 112 * MBYTE);
  __bf16* Wsbl = (__bf16*)(wsb + 120 * MBYTE);
  __bf16* Wsih = (__bf16*)(wsb + 128 * MBYTE);
  __bf16* Wsil = (__bf16*)(wsb + 136 * MBYTE);
  __bf16* Wsgh = (__bf16*)(wsb + 144 * MBYTE);
  __bf16* Wsgl = (__bf16*)(wsb + 152 * MBYTE);
  __bf16* H1h  = (__bf16*)(wsb + 160 * MBYTE);
  __bf16* H1l  = (__bf16*)(wsb + 168 * MBYTE);
  __bf16* MISSh = (__bf16*)(wsb + 176 * MBYTE);
  __bf16* MISSl = (__bf16*)(wsb + 184 * MBYTE);
  float*  YG  = (float*)(wsb + 192 * MBYTE);
  float*  YSC = (float*)(wsb + 208 * MBYTE);
  float*  YSB = (float*)(wsb + 216 * MBYTE);
  float*  YSI = (float*)(wsb + 224 * MBYTE);
  float*  YSG = (float*)(wsb + 232 * MBYTE);
  float* L0 = (float*)(wsb + 240 * MBYTE);
  float* L1 = L0 + NTOK * EDIM;
  float* L2 = L1 + NTOK * EDIM;
  float* L3 = L2 + NTOK * EDIM;
  float* L4 = L3 + NTOK * EDIM;
  float* meanp = L4 + NTOK * EDIM;

  float* dispatch = (float*)d_out;
  float* combine = dispatch + (size_t)NTOK * EDIM * CAPV;
  float* rp = combine + (size_t)NTOK * EDIM * CAPV;
  float* aux = rp + (size_t)NTOK * EDIM;

  hipMemsetAsync(d_out, 0, (size_t)out_size * sizeof(float), stream);
  hipMemsetAsync(meanp, 0, EDIM * sizeof(float), stream);

  dim3 blk(256);

  // 1) batched input splits (X, IMG, GEN)
  {
    SJob a{X, Xh, Xl}, b{IMG, IMGh, IMGl}, c{GEN, GENh, GENl};
    split3<<<3 * SPLIT_BLKS, blk, 0, stream>>>(a, b, c);
  }

  // 2) batched weight transpose+split (all 7 weights; depend only on inputs)
  {
    TJobs t;
    t.j[0] = {m_w1, Wmw1h, Wmw1l, HDIM};
    t.j[1] = {g_w1, Wgw1h, Wgw1l, HDIM};
    t.j[2] = {m_w2, Wmw2h, Wmw2l, HDIM};
    t.j[3] = {sc_w1, Wsch, Wscl, HHALF};
    t.j[4] = {sb_w1, Wsbh, Wsbl, HHALF};
    t.j[5] = {si_w1, Wsih, Wsil, HHALF};
    t.j[6] = {sg_w1, Wsgh, Wsgl, HHALF};
    tsplit<<<dim3(64, 64, 7), blk, 0, stream>>>(t);
  }

  // 3) GEMM stage A: all input-level GEMMs in one launch (768 blocks)
  {
    GJobs g;
    g.j[0] = {Xh, Xl, Wmw1h, Wmw1l, m_b1, nullptr, H1h, H1l, 1, HDIM, 0};
    g.j[1] = {Xh, Xl, Wgw1h, Wgw1l, g_b1, YG, nullptr, nullptr, 1, HDIM, 256};
    g.j[2] = {IMGh, IMGl, Wsih, Wsil, si_b1, YSI, nullptr, nullptr, 1, HHALF, 512};
    g.j[3] = {GENh, GENl, Wsgh, Wsgl, sg_b1, YSG, nullptr, nullptr, 1, HHALF, 640};
    g.njobs = 4;
    gemm_split<<<768, blk, 0, stream>>>(g);
  }

  // 4) GEMM stage B: miss = H1 @ m_w2 (no relu), split out
  {
    GJobs g;
    g.j[0] = {H1h, H1l, Wmw2h, Wmw2l, m_b2, nullptr, MISSh, MISSl, 0, HDIM, 0};
    g.njobs = 1;
    gemm_split<<<256, blk, 0, stream>>>(g);
  }

  // 5) GEMM stage C: sc/sb hiddens from miss
  {
    GJobs g;
    g.j[0] = {MISSh, MISSl, Wsch, Wscl, sc_b1, YSC, nullptr, nullptr, 1, HHALF, 0};
    g.j[1] = {MISSh, MISSl, Wsbh, Wsbl, sb_b1, YSB, nullptr, nullptr, 1, HHALF, 128};
    g.njobs = 2;
    gemm_split<<<256, blk, 0, stream>>>(g);
  }

  // 6) batched logits (all 5 routers)
  {
    LJobs l;
    l.j[0] = {YG, g_w2, g_b2, L0, HDIM};
    l.j[1] = {YSI, si_w2, si_b2, L1, HHALF};
    l.j[2] = {YSG, sg_w2, sg_b2, L2, HHALF};
    l.j[3] = {YSC, sc_w2, sc_b2, L3, HHALF};
    l.j[4] = {YSB, sb_w2, sb_b2, L4, HHALF};
    logits_kernel<<<5 * 256, blk, 0, stream>>>(l);
  }

  // 7) finalize + aux
  finalize_kernel<<<NTOK / 256, blk, 0, stream>>>(L0, L1, L2, L3, L4,
                                                  dispatch, combine, rp, meanp);
  aux_kernel<<<1, 64, 0, stream>>>(meanp, aux);
}